// Round 1
// baseline (124.461 us; speedup 1.0000x reference)
//
#include <hip/hip_runtime.h>
#include <stdint.h>

// BayesianLinear: out[b][o] = sum_i x[b][i] * (mu_w[o][i] + exp(ls_w[o][i])*eps_w[o][i])
//                 + (mu_b[o] + exp(ls_b[o])*eps_b[o])
// M=1024 (batch), N=4096 (out), K=4096 (in). fp32 in/out, bf16-tolerance harness
// => bf16 MFMA path (no fp32 MFMA on CDNA4).
//
// Phase 1: prep kernels  fp32 -> bf16 W (32MB), bf16 x (8MB), fp32 bias (16KB) in d_ws
// Phase 2: m97-structure GEMM (128x128 tile, BK=32, global_load_lds w=16, 16x16x32 bf16 MFMA)

#define IN_F  4096
#define OUT_F 4096
#define BATCH 1024

typedef unsigned short u16;
typedef __attribute__((ext_vector_type(8))) short bf16x8;  // 8 x bf16 (4 VGPRs)
typedef __attribute__((ext_vector_type(4))) float f32x4;   // MFMA accumulator

// RNE f32 -> bf16 (inputs finite; no NaN handling needed)
__device__ __forceinline__ u16 f2bf(float f) {
  uint32_t u = __float_as_uint(f);
  return (u16)((u + 0x7FFFu + ((u >> 16) & 1u)) >> 16);
}

// async global->LDS, 16B per lane. LDS dest is wave-uniform base + lane*16:
// our chunk mapping keeps lane order == LDS linear order.
__device__ __forceinline__ void gload_lds16(const void* g, void* l) {
  __builtin_amdgcn_global_load_lds(
      (const __attribute__((address_space(1))) void*)g,
      (__attribute__((address_space(3))) void*)l, 16, 0, 0);
}

// ---------------- prep kernels ----------------

__global__ void prep_w_kernel(const float* __restrict__ mu,
                              const float* __restrict__ ls,
                              const float* __restrict__ eps,
                              u16* __restrict__ wq) {
  const int64_t n4 = (int64_t)OUT_F * IN_F / 4;
  int64_t i = blockIdx.x * (int64_t)blockDim.x + threadIdx.x;
  const int64_t stride = (int64_t)gridDim.x * blockDim.x;
  for (; i < n4; i += stride) {
    float4 m = ((const float4*)mu)[i];
    float4 s = ((const float4*)ls)[i];
    float4 e = ((const float4*)eps)[i];
    ushort4 o;
    o.x = f2bf(fmaf(__expf(s.x), e.x, m.x));
    o.y = f2bf(fmaf(__expf(s.y), e.y, m.y));
    o.z = f2bf(fmaf(__expf(s.z), e.z, m.z));
    o.w = f2bf(fmaf(__expf(s.w), e.w, m.w));
    ((ushort4*)wq)[i] = o;
  }
}

__global__ void prep_x_kernel(const float* __restrict__ x, u16* __restrict__ xq) {
  const int64_t n4 = (int64_t)BATCH * IN_F / 4;
  int64_t i = blockIdx.x * (int64_t)blockDim.x + threadIdx.x;
  const int64_t stride = (int64_t)gridDim.x * blockDim.x;
  for (; i < n4; i += stride) {
    float4 v = ((const float4*)x)[i];
    ushort4 o;
    o.x = f2bf(v.x); o.y = f2bf(v.y); o.z = f2bf(v.z); o.w = f2bf(v.w);
    ((ushort4*)xq)[i] = o;
  }
}

__global__ void prep_b_kernel(const float* __restrict__ mu,
                              const float* __restrict__ ls,
                              const float* __restrict__ eps,
                              float* __restrict__ b) {
  int i = blockIdx.x * blockDim.x + threadIdx.x;
  if (i < OUT_F) b[i] = fmaf(__expf(ls[i]), eps[i], mu[i]);
}

// ---------------- GEMM (NT: C[m][n] = sum_k X[m][k]*W[n][k] + bias[n]) ----------------

#define BM 128
#define BN 128
#define BK 32
#define NBX (OUT_F / BN)  // 32 col-blocks; 8 row-blocks; 256 workgroups

__global__ void __launch_bounds__(256) gemm_kernel(
    const u16* __restrict__ X, const u16* __restrict__ W,
    const float* __restrict__ bias, float* __restrict__ out) {
  __shared__ u16 lds[BM * BK + BN * BK];  // A tile [128][32], B tile [128][32], 16KB
  u16* ldsA = lds;
  u16* ldsB = lds + BM * BK;

  const int tid = threadIdx.x;
  const int lane = tid & 63;
  const int wave = tid >> 6;           // 4 waves, 2x2
  const int wr = wave >> 1;            // wave row 0..1 (64 rows each)
  const int wc = wave & 1;             // wave col 0..1 (64 cols each)
  const int bx = blockIdx.x & (NBX - 1);
  const int by = blockIdx.x / NBX;

  const u16* Abase = X + (int64_t)by * BM * IN_F;
  const u16* Bbase = W + (int64_t)bx * BN * IN_F;

  f32x4 acc[4][4] = {};

  // staging: 512 chunks of 16B per tile (row = c>>2, k-chunk = c&3); LDS offset = c*16B
  const int c0 = tid, c1 = tid + 256;
  const int ar0 = c0 >> 2, ak0 = (c0 & 3) * 8;
  const int ar1 = c1 >> 2, ak1 = (c1 & 3) * 8;
  const int rl = lane & 15;            // fragment row/col within 16
  const int kh = (lane >> 4) * 8;      // k-half offset (8 elems)

  for (int k0 = 0; k0 < IN_F; k0 += BK) {
    __syncthreads();  // previous compute done before overwriting LDS
    gload_lds16(Abase + (int64_t)ar0 * IN_F + k0 + ak0, ldsA + c0 * 8);
    gload_lds16(Abase + (int64_t)ar1 * IN_F + k0 + ak1, ldsA + c1 * 8);
    gload_lds16(Bbase + (int64_t)ar0 * IN_F + k0 + ak0, ldsB + c0 * 8);
    gload_lds16(Bbase + (int64_t)ar1 * IN_F + k0 + ak1, ldsB + c1 * 8);
    __syncthreads();  // compiler emits vmcnt(0) drain before barrier

    bf16x8 af[4], bfv[4];
#pragma unroll
    for (int m = 0; m < 4; m++)
      af[m] = *(const bf16x8*)(ldsA + (wr * 64 + m * 16 + rl) * BK + kh);
#pragma unroll
    for (int n = 0; n < 4; n++)
      bfv[n] = *(const bf16x8*)(ldsB + (wc * 64 + n * 16 + rl) * BK + kh);
#pragma unroll
    for (int m = 0; m < 4; m++)
#pragma unroll
      for (int n = 0; n < 4; n++)
        acc[m][n] = __builtin_amdgcn_mfma_f32_16x16x32_bf16(af[m], bfv[n], acc[m][n], 0, 0, 0);
  }

  // epilogue: C/D layout col = lane&15, row = (lane>>4)*4 + reg  [m89-verified]
  const int gr0 = by * BM + wr * 64;
  const int gc0 = bx * BN + wc * 64;
  const int rh = (lane >> 4) * 4;
  float bv[4];
#pragma unroll
  for (int n = 0; n < 4; n++) bv[n] = bias[gc0 + n * 16 + rl];
#pragma unroll
  for (int m = 0; m < 4; m++) {
#pragma unroll
    for (int n = 0; n < 4; n++) {
      const int col = gc0 + n * 16 + rl;
#pragma unroll
      for (int j = 0; j < 4; j++)
        out[(int64_t)(gr0 + m * 16 + rh + j) * OUT_F + col] = acc[m][n][j] + bv[n];
    }
  }
}

// ---------------- launch ----------------

extern "C" void kernel_launch(void* const* d_in, const int* in_sizes, int n_in,
                              void* d_out, int out_size, void* d_ws, size_t ws_size,
                              hipStream_t stream) {
  const float* x     = (const float*)d_in[0];
  const float* eps_w = (const float*)d_in[1];
  const float* eps_b = (const float*)d_in[2];
  const float* mu_w  = (const float*)d_in[3];
  const float* ls_w  = (const float*)d_in[4];
  const float* mu_b  = (const float*)d_in[5];
  const float* ls_b  = (const float*)d_in[6];
  float* out = (float*)d_out;

  // workspace: W bf16 (32MB) | x bf16 (8MB) | bias fp32 (16KB)  => needs ~40MB
  u16* Wq = (u16*)d_ws;
  u16* Xq = Wq + (size_t)OUT_F * IN_F;
  float* bq = (float*)(Xq + (size_t)BATCH * IN_F);

  prep_w_kernel<<<2048, 256, 0, stream>>>(mu_w, ls_w, eps_w, Wq);
  prep_x_kernel<<<512, 256, 0, stream>>>(x, Xq);
  prep_b_kernel<<<16, 256, 0, stream>>>(mu_b, ls_b, eps_b, bq);
  gemm_kernel<<<(BATCH / BM) * NBX, 256, 0, stream>>>(Xq, Wq, bq, out);
}

// Round 2
// 97.175 us; speedup vs baseline: 1.2808x; 1.2808x over previous
//
#include <hip/hip_runtime.h>
#include <stdint.h>

// BayesianLinear: out = x @ (mu_w + exp(ls_w)*eps_w)^T + (mu_b + exp(ls_b)*eps_b)
// M=1024, N=4096, K=4096. fp32 in/out, bf16-tolerance harness => bf16 MFMA.
//
// R2: 64x128 tile, BK=64 -> 512 blocks (2/CU, was 1/CU); 8-slot XOR swizzle
// (inverse-swizzled global src + swizzled ds_read, LDS linear) kills the
// 8-way bank conflict of R1. bx=bid&31 co-locates B-panel sharers per XCD.

#define IN_F  4096
#define OUT_F 4096
#define BATCH 1024

typedef unsigned short u16;
typedef __attribute__((ext_vector_type(8))) short bf16x8;
typedef __attribute__((ext_vector_type(4))) float f32x4;

__device__ __forceinline__ u16 f2bf(float f) {
  uint32_t u = __float_as_uint(f);
  return (u16)((u + 0x7FFFu + ((u >> 16) & 1u)) >> 16);
}

__device__ __forceinline__ void gload_lds16(const void* g, void* l) {
  __builtin_amdgcn_global_load_lds(
      (const __attribute__((address_space(1))) void*)g,
      (__attribute__((address_space(3))) void*)l, 16, 0, 0);
}

// ---------------- prep kernels ----------------

__global__ void prep_w_kernel(const float* __restrict__ mu,
                              const float* __restrict__ ls,
                              const float* __restrict__ eps,
                              u16* __restrict__ wq) {
  const int64_t n4 = (int64_t)OUT_F * IN_F / 4;
  int64_t i = blockIdx.x * (int64_t)blockDim.x + threadIdx.x;
  const int64_t stride = (int64_t)gridDim.x * blockDim.x;
  for (; i < n4; i += stride) {
    float4 m = ((const float4*)mu)[i];
    float4 s = ((const float4*)ls)[i];
    float4 e = ((const float4*)eps)[i];
    ushort4 o;
    o.x = f2bf(fmaf(__expf(s.x), e.x, m.x));
    o.y = f2bf(fmaf(__expf(s.y), e.y, m.y));
    o.z = f2bf(fmaf(__expf(s.z), e.z, m.z));
    o.w = f2bf(fmaf(__expf(s.w), e.w, m.w));
    ((ushort4*)wq)[i] = o;
  }
}

// x -> bf16, plus bias prep folded in (first OUT_F threads)
__global__ void prep_xb_kernel(const float* __restrict__ x,
                               const float* __restrict__ mu_b,
                               const float* __restrict__ ls_b,
                               const float* __restrict__ eps_b,
                               u16* __restrict__ xq, float* __restrict__ bq) {
  int64_t i = blockIdx.x * (int64_t)blockDim.x + threadIdx.x;
  if (i < OUT_F) bq[i] = fmaf(__expf(ls_b[i]), eps_b[i], mu_b[i]);
  const int64_t n4 = (int64_t)BATCH * IN_F / 4;
  const int64_t stride = (int64_t)gridDim.x * blockDim.x;
  for (; i < n4; i += stride) {
    float4 v = ((const float4*)x)[i];
    ushort4 o;
    o.x = f2bf(v.x); o.y = f2bf(v.y); o.z = f2bf(v.z); o.w = f2bf(v.w);
    ((ushort4*)xq)[i] = o;
  }
}

// ---------------- GEMM (NT: C[m][n] = sum_k X[m][k]*W[n][k] + bias[n]) ----------------

#define BM 64
#define BN 128
#define BK 64
#define NBX (OUT_F / BN)   // 32 col-blocks x 16 row-blocks = 512 workgroups (2/CU)

__global__ void __launch_bounds__(256) gemm_kernel(
    const u16* __restrict__ X, const u16* __restrict__ W,
    const float* __restrict__ bias, float* __restrict__ out) {
  __shared__ u16 ldsA[BM * BK];  //  8 KB, rows of 128B = 8 x 16B slots
  __shared__ u16 ldsB[BN * BK];  // 16 KB

  const int tid = threadIdx.x;
  const int lane = tid & 63;
  const int wave = tid >> 6;          // 4 waves: 2x2
  const int wr = wave >> 1;           // 0..1  (32 rows each)
  const int wc = wave & 1;            // 0..1  (64 cols each)
  const int bx = blockIdx.x & (NBX - 1);   // same-bx blocks share XCD (id%8)
  const int by = blockIdx.x / NBX;

  const u16* Abase = X + (int64_t)by * BM * IN_F;
  const u16* Bbase = W + (int64_t)bx * BN * IN_F;

  f32x4 acc[2][4] = {};

  const int rl = lane & 15;           // fragment row within 16
  const int lk = lane >> 4;           // k-group 0..3 (8 elems each)

  // staging chunk decode: chunk c -> row = c>>3, phys slot = c&7.
  // LDS is linear (c*16B); the DATA for phys slot sp is global slot sp^(row&7)
  // so that a reader XORing the same mask finds logical slot s at sp = s^(row&7).
  for (int k0 = 0; k0 < IN_F; k0 += BK) {
    __syncthreads();
#pragma unroll
    for (int j = 0; j < 2; j++) {     // A: 512 chunks / 256 threads
      const int c = tid + j * 256, r = c >> 3, sp = c & 7;
      gload_lds16(Abase + (int64_t)r * IN_F + k0 + ((sp ^ (r & 7)) * 8), ldsA + c * 8);
    }
#pragma unroll
    for (int j = 0; j < 4; j++) {     // B: 1024 chunks / 256 threads
      const int c = tid + j * 256, r = c >> 3, sp = c & 7;
      gload_lds16(Bbase + (int64_t)r * IN_F + k0 + ((sp ^ (r & 7)) * 8), ldsB + c * 8);
    }
    __syncthreads();

    bf16x8 af[2][2], bfv[2][4];
#pragma unroll
    for (int kk = 0; kk < 2; kk++) {
#pragma unroll
      for (int m = 0; m < 2; m++) {
        const int R = wr * 32 + m * 16 + rl;
        const int slot = kk * 4 + lk;
        af[kk][m] = *(const bf16x8*)(ldsA + R * BK + ((slot ^ (R & 7)) * 8));
      }
#pragma unroll
      for (int n = 0; n < 4; n++) {
        const int R = wc * 64 + n * 16 + rl;
        const int slot = kk * 4 + lk;
        bfv[kk][n] = *(const bf16x8*)(ldsB + R * BK + ((slot ^ (R & 7)) * 8));
      }
    }
#pragma unroll
    for (int kk = 0; kk < 2; kk++)
#pragma unroll
      for (int m = 0; m < 2; m++)
#pragma unroll
        for (int n = 0; n < 4; n++)
          acc[m][n] = __builtin_amdgcn_mfma_f32_16x16x32_bf16(af[kk][m], bfv[kk][n], acc[m][n], 0, 0, 0);
  }

  // epilogue: C/D layout col = lane&15, row = (lane>>4)*4 + reg  [m89-verified]
  const int gr0 = by * BM + wr * 32;
  const int gc0 = bx * BN + wc * 64;
  const int rh = (lane >> 4) * 4;
  float bv[4];
#pragma unroll
  for (int n = 0; n < 4; n++) bv[n] = bias[gc0 + n * 16 + rl];
#pragma unroll
  for (int m = 0; m < 2; m++) {
#pragma unroll
    for (int n = 0; n < 4; n++) {
      const int col = gc0 + n * 16 + rl;
#pragma unroll
      for (int j = 0; j < 4; j++)
        out[(int64_t)(gr0 + m * 16 + rh + j) * OUT_F + col] = acc[m][n][j] + bv[n];
    }
  }
}

// ---------------- launch ----------------

extern "C" void kernel_launch(void* const* d_in, const int* in_sizes, int n_in,
                              void* d_out, int out_size, void* d_ws, size_t ws_size,
                              hipStream_t stream) {
  const float* x     = (const float*)d_in[0];
  const float* eps_w = (const float*)d_in[1];
  const float* eps_b = (const float*)d_in[2];
  const float* mu_w  = (const float*)d_in[3];
  const float* ls_w  = (const float*)d_in[4];
  const float* mu_b  = (const float*)d_in[5];
  const float* ls_b  = (const float*)d_in[6];
  float* out = (float*)d_out;

  u16* Wq = (u16*)d_ws;                              // 32 MB
  u16* Xq = Wq + (size_t)OUT_F * IN_F;               //  8 MB
  float* bq = (float*)(Xq + (size_t)BATCH * IN_F);   // 16 KB

  prep_w_kernel<<<2048, 256, 0, stream>>>(mu_w, ls_w, eps_w, Wq);
  prep_xb_kernel<<<512, 256, 0, stream>>>(x, mu_b, ls_b, eps_b, Xq, bq);
  gemm_kernel<<<(BATCH / BM) * NBX, 256, 0, stream>>>(Xq, Wq, bq, out);
}